// Round 14
// baseline (1022.934 us; speedup 1.0000x reference)
//
#include <hip/hip_runtime.h>
#include <hip/hip_bf16.h>
#include <stdint.h>
#include <stddef.h>

// B=2, T=2048, D=2048, H=16, DH=128, F=8192, M=B*T=4096
using bf16_t = __hip_bfloat16;
typedef __attribute__((ext_vector_type(8))) short short8;
typedef __attribute__((ext_vector_type(4))) short short4v;
typedef __attribute__((ext_vector_type(4))) float f32x4;

__device__ __forceinline__ void gload_lds16(const void* g, void* l) {
  __builtin_amdgcn_global_load_lds((const __attribute__((address_space(1))) void*)g,
                                   (__attribute__((address_space(3))) void*)l,
                                   16, 0, 0);
}

// ---------- transpose + f32->bf16 convert: out[N][K] = in[K][N] ----------
__global__ __launch_bounds__(256) void k_transpose_cvt(const float* __restrict__ in,
                                                       bf16_t* __restrict__ out,
                                                       int K, int N) {
  __shared__ float tile[64][65];
  int n0 = blockIdx.x * 64, k0 = blockIdx.y * 64;
  int t = threadIdx.x;
  int tr = t >> 4, tc = t & 15;
#pragma unroll
  for (int i = 0; i < 4; ++i) {
    float4 v = *(const float4*)(in + (size_t)(k0 + tr + i * 16) * N + n0 + tc * 4);
    tile[tr + i * 16][tc * 4 + 0] = v.x;
    tile[tr + i * 16][tc * 4 + 1] = v.y;
    tile[tr + i * 16][tc * 4 + 2] = v.z;
    tile[tr + i * 16][tc * 4 + 3] = v.w;
  }
  __syncthreads();
#pragma unroll
  for (int i = 0; i < 4; ++i) {
    int nn = tr + i * 16;
    short4v s;
    s[0] = (short)__bfloat16_as_ushort(__float2bfloat16(tile[tc * 4 + 0][nn]));
    s[1] = (short)__bfloat16_as_ushort(__float2bfloat16(tile[tc * 4 + 1][nn]));
    s[2] = (short)__bfloat16_as_ushort(__float2bfloat16(tile[tc * 4 + 2][nn]));
    s[3] = (short)__bfloat16_as_ushort(__float2bfloat16(tile[tc * 4 + 3][nn]));
    *(short4v*)(out + (size_t)(n0 + nn) * K + k0 + tc * 4) = s;
  }
}

// ---------- layernorm f32 -> bf16, one block per row of 2048 ----------
__global__ __launch_bounds__(256) void k_layernorm(const float* __restrict__ x,
                                                   const float* __restrict__ gam,
                                                   const float* __restrict__ bet,
                                                   bf16_t* __restrict__ out) {
  int row = blockIdx.x, t = threadIdx.x;
  const float4* xr = (const float4*)(x + (size_t)row * 2048);
  float4 a = xr[t], b = xr[t + 256];
  float s  = a.x + a.y + a.z + a.w + b.x + b.y + b.z + b.w;
  float s2 = a.x*a.x + a.y*a.y + a.z*a.z + a.w*a.w
           + b.x*b.x + b.y*b.y + b.z*b.z + b.w*b.w;
#pragma unroll
  for (int off = 32; off >= 1; off >>= 1) {
    s  += __shfl_xor(s, off);
    s2 += __shfl_xor(s2, off);
  }
  __shared__ float red[8];
  if ((t & 63) == 0) { red[t >> 6] = s; red[4 + (t >> 6)] = s2; }
  __syncthreads();
  float S  = red[0] + red[1] + red[2] + red[3];
  float S2 = red[4] + red[5] + red[6] + red[7];
  float mu = S * (1.0f / 2048.0f);
  float var = S2 * (1.0f / 2048.0f) - mu * mu;
  float rstd = rsqrtf(var + 1e-6f);
  const float4* gv = (const float4*)gam;
  const float4* bv = (const float4*)bet;
  float4 g1 = gv[t], g2 = gv[t + 256], c1 = bv[t], c2 = bv[t + 256];
  bf16_t* orow = out + (size_t)row * 2048;
  orow[4*t + 0]    = __float2bfloat16((a.x - mu) * rstd * g1.x + c1.x);
  orow[4*t + 1]    = __float2bfloat16((a.y - mu) * rstd * g1.y + c1.y);
  orow[4*t + 2]    = __float2bfloat16((a.z - mu) * rstd * g1.z + c1.z);
  orow[4*t + 3]    = __float2bfloat16((a.w - mu) * rstd * g1.w + c1.w);
  orow[1024 + 4*t + 0] = __float2bfloat16((b.x - mu) * rstd * g2.x + c2.x);
  orow[1024 + 4*t + 1] = __float2bfloat16((b.y - mu) * rstd * g2.y + c2.y);
  orow[1024 + 4*t + 2] = __float2bfloat16((b.z - mu) * rstd * g2.z + c2.z);
  orow[1024 + 4*t + 3] = __float2bfloat16((b.w - mu) * rstd * g2.w + c2.w);
}

// ---------- direct-B GEMM: C[M,N] = A[M,K] x Bt[N,K] (bf16) ----------
// 128x128 tile, 256 thr = 4 waves (2M x 2N), per-wave C = 64x64. BK=64.
// A through LDS (3 x 16KB bufs, pre-swizzled source, 2-K-tile flight).
// B DIRECT global->register (no LDS, no barrier): per wave 8 global b128/K-tile,
// 16 rows x 64B contiguous each; B-slice is per-XCD-L2-resident via nsub mapping.
// One s_barrier + one counted vmcnt per K-tile; compiler auto-counts the waits
// for the B registers (it models both its loads and the DMA in vmcnt).
// EPI: 0 = bf16+bias ; 1 = bf16+bias+gelu ; 3 = f32 atomicAdd (+bias on chunk 0);
//      4 = QKV: n0<4096 -> bf16+bias; n0>=4096 -> packed vT store only.
template <int EPI>
__global__ __launch_bounds__(256, 2) void k_gemm10(const bf16_t* __restrict__ A,
                                                   const bf16_t* __restrict__ Bt,
                                                   const float* __restrict__ bias,
                                                   bf16_t* __restrict__ Cb,
                                                   float* __restrict__ Cf,
                                                   bf16_t* __restrict__ Vt,
                                                   int Ndim, int LDA, int LDB,
                                                   int Kdim, int nsub) {
  __shared__ __align__(16) char lds[49152];      // 3 x 16KB A buffers
  int orig = blockIdx.x;
  int xcd = orig & 7;                            // HW round-robin XCD
  int i = orig >> 3;
  int m = i & 31;                                // 32 m-tiles, m INNER
  int j = i >> 5;
  int n_local = j % nsub;
  int chunk = j / nsub;
  int m0 = m * 128;
  int n0 = (xcd * nsub + n_local) * 128;
  int tid = threadIdx.x;
  int w = tid >> 6, lane = tid & 63;
  int lr = lane & 15, lk = lane >> 4;
  int wr = w >> 1, wc = w & 1;

  const bf16_t* Ag = A + (size_t)m0 * LDA + (size_t)chunk * Kdim;
  const bf16_t* Bg = Bt + (size_t)n0 * LDB + (size_t)chunk * Kdim;
  // A staging sources: 4 gloads/thread/K-tile; rows g*32 + (tid>>3), chunk pre-swizzled
  int swz = ((tid & 7) ^ ((tid >> 3) & 7)) << 3;
  const bf16_t* pA0 = Ag + (size_t)((tid >> 3) +  0) * LDA + swz;
  const bf16_t* pA1 = Ag + (size_t)((tid >> 3) + 32) * LDA + swz;
  const bf16_t* pA2 = Ag + (size_t)((tid >> 3) + 64) * LDA + swz;
  const bf16_t* pA3 = Ag + (size_t)((tid >> 3) + 96) * LDA + swz;
  int dstb = tid * 16;
  // B direct per-lane bases (advance +64 elems per K-tile)
  const bf16_t* pB0 = Bg + (size_t)(wc * 64 +  0 + lr) * LDB + lk * 8;
  const bf16_t* pB1 = Bg + (size_t)(wc * 64 + 16 + lr) * LDB + lk * 8;
  const bf16_t* pB2 = Bg + (size_t)(wc * 64 + 32 + lr) * LDB + lk * 8;
  const bf16_t* pB3 = Bg + (size_t)(wc * 64 + 48 + lr) * LDB + lk * 8;
  // loop-invariant swizzled A-read offsets
  int ch0 = ((lk)     ^ (lr & 7)) * 16;
  int ch1 = ((4 + lk) ^ (lr & 7)) * 16;
  int arow[4];
#pragma unroll
  for (int mf = 0; mf < 4; ++mf) arow[mf] = (wr * 64 + mf * 16 + lr) * 128;

  f32x4 acc[4][4];
#pragma unroll
  for (int ii = 0; ii < 4; ++ii)
#pragma unroll
    for (int jj = 0; jj < 4; ++jj) acc[ii][jj] = (f32x4){0.f, 0.f, 0.f, 0.f};
  short8 bqA[4][2], bqB[4][2];

#define STAGEA(off) do { \
    gload_lds16(pA0, lds + (off) + dstb);          \
    gload_lds16(pA1, lds + (off) + 4096 + dstb);   \
    gload_lds16(pA2, lds + (off) + 8192 + dstb);   \
    gload_lds16(pA3, lds + (off) + 12288 + dstb);  \
    pA0 += 64; pA1 += 64; pA2 += 64; pA3 += 64; } while (0)
#define LOADB(SET) do { \
    SET[0][0] = *(const short8*)(pB0);      SET[0][1] = *(const short8*)(pB0 + 32); \
    SET[1][0] = *(const short8*)(pB1);      SET[1][1] = *(const short8*)(pB1 + 32); \
    SET[2][0] = *(const short8*)(pB2);      SET[2][1] = *(const short8*)(pB2 + 32); \
    SET[3][0] = *(const short8*)(pB3);      SET[3][1] = *(const short8*)(pB3 + 32); \
    pB0 += 64; pB1 += 64; pB2 += 64; pB3 += 64; } while (0)
#define KS(SET, ks, CH) do { \
    short8 af0 = *(const short8*)(lds + rd + arow[0] + (CH)); \
    short8 af1 = *(const short8*)(lds + rd + arow[1] + (CH)); \
    short8 af2 = *(const short8*)(lds + rd + arow[2] + (CH)); \
    short8 af3 = *(const short8*)(lds + rd + arow[3] + (CH)); \
    _Pragma("unroll") for (int nf = 0; nf < 4; ++nf) { \
      acc[0][nf] = __builtin_amdgcn_mfma_f32_16x16x32_bf16(af0, SET[nf][ks], acc[0][nf], 0, 0, 0); \
      acc[1][nf] = __builtin_amdgcn_mfma_f32_16x16x32_bf16(af1, SET[nf][ks], acc[1][nf], 0, 0, 0); \
      acc[2][nf] = __builtin_amdgcn_mfma_f32_16x16x32_bf16(af2, SET[nf][ks], acc[2][nf], 0, 0, 0); \
      acc[3][nf] = __builtin_amdgcn_mfma_f32_16x16x32_bf16(af3, SET[nf][ks], acc[3][nf], 0, 0, 0); } } while (0)
#define ENDTILE(VMN) do { \
    asm volatile("s_waitcnt lgkmcnt(0)" ::: "memory"); \
    asm volatile("s_waitcnt vmcnt(%0)" :: "i"(VMN) : "memory"); \
    asm volatile("s_barrier" ::: "memory"); \
    rd = (rd == 32768) ? 0 : rd + 16384; \
    wrb = (wrb == 32768) ? 0 : wrb + 16384; } while (0)

  int rd = 0, wrb = 32768;
  const int NT = Kdim >> 6;                      // even for all our shapes
  // prologue: A(0)->buf0, B(0)->bqA, A(1)->buf1; vmcnt(12) retires A(0) only
  STAGEA(0);
  LOADB(bqA);
  STAGEA(16384);
  asm volatile("s_waitcnt vmcnt(12)" ::: "memory");
  asm volatile("s_barrier" ::: "memory");

  for (int t = 0; t < NT - 2; t += 2) {
    LOADB(bqB);                                  // B(t+1)
    STAGEA(wrb);                                 // A(t+2)
    KS(bqA, 0, ch0); KS(bqA, 1, ch1);
    ENDTILE(12);                                 // A(t+1) landed; B(t+1),A(t+2) in flight
    LOADB(bqA);                                  // B(t+2)
    STAGEA(wrb);                                 // A(t+3)
    KS(bqB, 0, ch0); KS(bqB, 1, ch1);
    ENDTILE(12);
  }
  {                                              // t = NT-2: stage B(NT-1) only
    LOADB(bqB);
    KS(bqA, 0, ch0); KS(bqA, 1, ch1);
    ENDTILE(8);                                  // A(NT-1) landed
  }
  {                                              // t = NT-1: compute only
    KS(bqB, 0, ch0); KS(bqB, 1, ch1);
    asm volatile("s_waitcnt lgkmcnt(0)" ::: "memory");
  }
#undef STAGEA
#undef LOADB
#undef KS
#undef ENDTILE

  if (EPI == 4 && n0 >= 4096) {
#pragma unroll
    for (int mf = 0; mf < 4; ++mf) {
#pragma unroll
      for (int nf = 0; nf < 4; ++nf) {
        int cl = n0 + wc * 64 + nf * 16 + lr;
        int d = cl - 4096;
        int hh = d >> 7, dh = d & 127;
        int rwb = m0 + wr * 64 + mf * 16 + lk * 4;
        int bb = rwb >> 11, tt = rwb & 2047;
        float bs = bias[cl];
        short4v s;
#pragma unroll
        for (int r = 0; r < 4; ++r)
          s[r] = (short)__bfloat16_as_ushort(__float2bfloat16(acc[mf][nf][r] + bs));
        *(short4v*)(Vt + ((size_t)(bb * 16 + hh) * 128 + dh) * 2048 + tt) = s;
      }
    }
    return;
  }
#pragma unroll
  for (int mf = 0; mf < 4; ++mf) {
#pragma unroll
    for (int nf = 0; nf < 4; ++nf) {
#pragma unroll
      for (int r = 0; r < 4; ++r) {
        int rw = m0 + wr * 64 + mf * 16 + lk * 4 + r;
        int cl = n0 + wc * 64 + nf * 16 + lr;
        float v = acc[mf][nf][r];
        size_t gi = (size_t)rw * Ndim + cl;
        if (EPI == 0 || EPI == 4) {
          Cb[gi] = __float2bfloat16(v + bias[cl]);
        } else if (EPI == 1) {
          float vv = v + bias[cl];
          float u = vv * (vv * vv * 0.044715f + 1.0f) * 0.7978845608028654f;
          float gl = 0.5f * vv * (1.0f + tanhf(u));
          Cb[gi] = __float2bfloat16(gl);
        } else {
          float add = v + (chunk == 0 ? bias[cl] : 0.0f);
          atomicAdd(&Cf[gi], add);
        }
      }
    }
  }
}

// ---------- causal flash attention + residual add (R13, unchanged) ----------
__global__ __launch_bounds__(256, 2) void k_attn(const bf16_t* __restrict__ qkv,
                                                 const bf16_t* __restrict__ vT,
                                                 const float* __restrict__ x,
                                                 float* __restrict__ out) {
  __shared__ __align__(16) bf16_t Pl[4][32][40];
  int j = blockIdx.x;
  int bh = j & 31;
  int cq = j >> 5;
  int b = bh >> 4, h = bh & 15;
  int w = threadIdx.x >> 6, lane = threadIdx.x & 63;
  int lr = lane & 15, lk = lane >> 4;
  int c = (w == 0) ? cq : (w == 1) ? (63 - cq) : (w == 2) ? (31 - cq) : (32 + cq);
  int q0 = c * 32;
  const bf16_t* qb = qkv + (size_t)(b * 2048) * 6144 + h * 128;
  const bf16_t* kb = qb + 2048;
  const bf16_t* vb = vT + (size_t)(b * 16 + h) * 128 * 2048;
  short8 qf[2][4];
#pragma unroll
  for (int qg = 0; qg < 2; ++qg)
#pragma unroll
    for (int d4 = 0; d4 < 4; ++d4)
      qf[qg][d4] = *(const short8*)(qb + (size_t)(q0 + qg * 16 + lr) * 6144 + d4 * 32 + lk * 8);
  float m[2][4], l[2][4];
#pragma unroll
  for (int qg = 0; qg < 2; ++qg)
#pragma unroll
    for (int r = 0; r < 4; ++r) { m[qg][r] = -1e30f; l[qg][r] = 0.f; }
  f32x4 o[2][8] = {};
  int nkt = c + 1;
  const float sc = 0.08838834764831845f;
  short8 kf[2][4], vf[8];
#pragma unroll
  for (int nt = 0; nt < 2; ++nt)
#pragma unroll
    for (int d4 = 0; d4 < 4; ++d4)
      kf[nt][d4] = *(const short8*)(kb + (size_t)(nt * 16 + lr) * 6144 + d4 * 32 + lk * 8);
#pragma unroll
  for (int d8 = 0; d8 < 8; ++d8)
    vf[d8] = *(const short8*)(vb + (size_t)(d8 * 16 + lr) * 2048 + lk * 8);

  for (int kt = 0; kt < nkt; ++kt) {
    int tk0 = kt * 32;
    f32x4 s[2][2] = {};
    __builtin_amdgcn_s_setprio(1);
#pragma unroll
    for (int d4 = 0; d4 < 4; ++d4)
#pragma unroll
      for (int qg = 0; qg < 2; ++qg)
#pragma unroll
        for (int nt = 0; nt < 2; ++nt)
          s[qg][nt] = __builtin_amdgcn_mfma_f32_16x16x32_bf16(qf[qg][d4], kf[nt][d4], s[qg][nt], 0, 0, 0);
    __builtin_amdgcn_s_setprio(0);
    if (kt + 1 < nkt) {
      int tn = tk0 + 32;
#pragma unroll
      for (int nt = 0; nt < 2; ++nt)
#pragma unroll
        for (int d4 = 0; d4 < 4; ++d4)
          kf[nt][d4] = *(const short8*)(kb + (size_t)(tn + nt * 16 + lr) * 6144 + d4 * 32 + lk * 8);
    }
#pragma unroll
    for (int qg = 0; qg < 2; ++qg) {
      float sv[2][4], mt[4];
#pragma unroll
      for (int r = 0; r < 4; ++r) {
        int qr = q0 + qg * 16 + lk * 4 + r;
#pragma unroll
        for (int nt = 0; nt < 2; ++nt) {
          float v = s[qg][nt][r] * sc;
          int kc = tk0 + nt * 16 + lr;
          sv[nt][r] = (kc > qr) ? -1e30f : v;
        }
        mt[r] = fmaxf(sv[0][r], sv[1][r]);
      }
#pragma unroll
      for (int off = 1; off < 16; off <<= 1)
#pragma unroll
        for (int r = 0; r < 4; ++r) mt[r] = fmaxf(mt[r], __shfl_xor(mt[r], off));
      float alpha[4], rs[4];
#pragma unroll
      for (int r = 0; r < 4; ++r) {
        float mn = fmaxf(m[qg][r], mt[r]);
        alpha[r] = __expf(m[qg][r] - mn);
        m[qg][r] = mn;
      }
#pragma unroll
      for (int r = 0; r < 4; ++r) {
        float p0 = __expf(sv[0][r] - m[qg][r]);
        float p1 = __expf(sv[1][r] - m[qg][r]);
        rs[r] = p0 + p1;
        Pl[w][qg * 16 + lk * 4 + r][lr]      = __float2bfloat16(p0);
        Pl[w][qg * 16 + lk * 4 + r][16 + lr] = __float2bfloat16(p1);
      }
#pragma unroll
      for (int off = 1; off < 16; off <<= 1)
#pragma unroll
        for (int r = 0; r < 4; ++r) rs[r] += __shfl_xor(rs[r], off);
#pragma unroll
      for (int r = 0; r < 4; ++r) l[qg][r] = l[qg][r] * alpha[r] + rs[r];
#pragma unroll
      for (int d8 = 0; d8 < 8; ++d8)
#pragma unroll
        for (int r = 0; r < 4; ++r) o[qg][d8][r] *= alpha[r];
    }
    asm volatile("s_waitcnt lgkmcnt(0)" ::: "memory");
    short8 pf[2];
#pragma unroll
    for (int qg = 0; qg < 2; ++qg)
      pf[qg] = *(const short8*)(&Pl[w][qg * 16 + lr][lk * 8]);
    __builtin_amdgcn_s_setprio(1);
#pragma unroll
    for (int d8 = 0; d8 < 8; ++d8)
#pragma unroll
      for (int qg = 0; qg < 2; ++qg)
        o[qg][d8] = __builtin_amdgcn_mfma_f32_16x16x32_bf16(pf[qg], vf[d8], o[qg][d8], 0, 0, 0);
    __builtin_amdgcn_s_setprio(0);
    if (kt + 1 < nkt) {
      int tn = tk0 + 32;
#pragma unroll
      for (int d8 = 0; d8 < 8; ++d8)
        vf[d8] = *(const short8*)(vb + (size_t)(d8 * 16 + lr) * 2048 + tn + lk * 8);
    }
  }
#pragma unroll
  for (int qg = 0; qg < 2; ++qg)
#pragma unroll
    for (int d8 = 0; d8 < 8; ++d8)
#pragma unroll
      for (int r = 0; r < 4; ++r) {
        int qr = q0 + qg * 16 + lk * 4 + r;
        int cl = h * 128 + d8 * 16 + lr;
        size_t gi = (size_t)(b * 2048 + qr) * 2048 + cl;
        out[gi] = x[gi] + o[qg][d8][r] / l[qg][r];
      }
}

extern "C" void kernel_launch(void* const* d_in, const int* in_sizes, int n_in,
                              void* d_out, int out_size, void* d_ws, size_t ws_size,
                              hipStream_t stream) {
  const float* x    = (const float*)d_in[0];
  const float* ln1s = (const float*)d_in[1];
  const float* ln1b = (const float*)d_in[2];
  const float* wqkv = (const float*)d_in[3];
  const float* bqkv = (const float*)d_in[4];
  const float* ln2s = (const float*)d_in[5];
  const float* ln2b = (const float*)d_in[6];
  const float* w1   = (const float*)d_in[7];
  const float* b1   = (const float*)d_in[8];
  const float* w2   = (const float*)d_in[9];
  const float* b2   = (const float*)d_in[10];
  float* out = (float*)d_out;
  char* ws = (char*)d_ws;

  // ws layout (bytes): r@0 16MB; qkv@16MB 48MB (V third unused); w1T@64MB 32MB;
  // w2T@96MB 32MB; h@128MB 64MB (clobbers wqkvT+vT after attention);
  // wqkvT@128MB 24MB (dead before h); vT@160MB 16MB (dead before h).
  bf16_t* r     = (bf16_t*)(ws + 0);
  bf16_t* qkv   = (bf16_t*)(ws + 16777216);
  bf16_t* w1T   = (bf16_t*)(ws + 67108864);
  bf16_t* w2T   = (bf16_t*)(ws + 100663296);
  bf16_t* h     = (bf16_t*)(ws + 134217728);
  bf16_t* wqkvT = (bf16_t*)(ws + 134217728);
  bf16_t* vT    = (bf16_t*)(ws + 167772160);

  // weight transposes (f32 [K][N] -> bf16 [N][K])
  k_transpose_cvt<<<dim3(96, 32),  256, 0, stream>>>(wqkv, wqkvT, 2048, 6144);
  k_transpose_cvt<<<dim3(128, 32), 256, 0, stream>>>(w1,   w1T,   2048, 8192);
  k_transpose_cvt<<<dim3(32, 128), 256, 0, stream>>>(w2,   w2T,   8192, 2048);
  // LN1
  k_layernorm<<<4096, 256, 0, stream>>>(x, ln1s, ln1b, r);
  // QKV (fused V-transpose): 48 n-tiles -> nsub=6 (B-slice 3MB/XCD); 32x48 = 1536 blocks
  k_gemm10<4><<<1536, 256, 0, stream>>>(r, wqkvT, bqkv, qkv, nullptr, vT, 6144, 2048, 2048, 2048, 6);
  // attention + residual (writes every element of d_out)
  k_attn<<<512, 256, 0, stream>>>(qkv, vT, x, out);
  // LN2 on x2 = d_out
  k_layernorm<<<4096, 256, 0, stream>>>(out, ln2s, ln2b, r);
  // MLP1: 64 n-tiles -> nsub=8 (4MB/XCD); 32x64 = 2048 blocks
  k_gemm10<1><<<2048, 256, 0, stream>>>(r, w1T, b1, h, nullptr, nullptr, 8192, 2048, 2048, 2048, 8);
  // MLP2 split-K=2, atomicAdd epilogue: 16 n-tiles -> nsub=2; 32x16x2 = 1024 blocks
  k_gemm10<3><<<1024, 256, 0, stream>>>(h, w2T, b2, nullptr, out, nullptr, 2048, 8192, 8192, 4096, 2);
}

// Round 15
// 647.314 us; speedup vs baseline: 1.5803x; 1.5803x over previous
//
#include <hip/hip_runtime.h>
#include <hip/hip_bf16.h>
#include <stdint.h>
#include <stddef.h>

// B=2, T=2048, D=2048, H=16, DH=128, F=8192, M=B*T=4096
using bf16_t = __hip_bfloat16;
typedef __attribute__((ext_vector_type(8))) short short8;
typedef __attribute__((ext_vector_type(4))) short short4v;
typedef __attribute__((ext_vector_type(4))) float f32x4;

__device__ __forceinline__ void gload_lds16(const void* g, void* l) {
  __builtin_amdgcn_global_load_lds((const __attribute__((address_space(1))) void*)g,
                                   (__attribute__((address_space(3))) void*)l,
                                   16, 0, 0);
}

// ---------- transpose + f32->bf16 convert: out[N][K] = in[K][N] ----------
__global__ __launch_bounds__(256) void k_transpose_cvt(const float* __restrict__ in,
                                                       bf16_t* __restrict__ out,
                                                       int K, int N) {
  __shared__ float tile[64][65];
  int n0 = blockIdx.x * 64, k0 = blockIdx.y * 64;
  int t = threadIdx.x;
  int tr = t >> 4, tc = t & 15;
#pragma unroll
  for (int i = 0; i < 4; ++i) {
    float4 v = *(const float4*)(in + (size_t)(k0 + tr + i * 16) * N + n0 + tc * 4);
    tile[tr + i * 16][tc * 4 + 0] = v.x;
    tile[tr + i * 16][tc * 4 + 1] = v.y;
    tile[tr + i * 16][tc * 4 + 2] = v.z;
    tile[tr + i * 16][tc * 4 + 3] = v.w;
  }
  __syncthreads();
#pragma unroll
  for (int i = 0; i < 4; ++i) {
    int nn = tr + i * 16;
    short4v s;
    s[0] = (short)__bfloat16_as_ushort(__float2bfloat16(tile[tc * 4 + 0][nn]));
    s[1] = (short)__bfloat16_as_ushort(__float2bfloat16(tile[tc * 4 + 1][nn]));
    s[2] = (short)__bfloat16_as_ushort(__float2bfloat16(tile[tc * 4 + 2][nn]));
    s[3] = (short)__bfloat16_as_ushort(__float2bfloat16(tile[tc * 4 + 3][nn]));
    *(short4v*)(out + (size_t)(n0 + nn) * K + k0 + tc * 4) = s;
  }
}

// ---------- layernorm f32 -> bf16, one block per row of 2048 ----------
__global__ __launch_bounds__(256) void k_layernorm(const float* __restrict__ x,
                                                   const float* __restrict__ gam,
                                                   const float* __restrict__ bet,
                                                   bf16_t* __restrict__ out) {
  int row = blockIdx.x, t = threadIdx.x;
  const float4* xr = (const float4*)(x + (size_t)row * 2048);
  float4 a = xr[t], b = xr[t + 256];
  float s  = a.x + a.y + a.z + a.w + b.x + b.y + b.z + b.w;
  float s2 = a.x*a.x + a.y*a.y + a.z*a.z + a.w*a.w
           + b.x*b.x + b.y*b.y + b.z*b.z + b.w*b.w;
#pragma unroll
  for (int off = 32; off >= 1; off >>= 1) {
    s  += __shfl_xor(s, off);
    s2 += __shfl_xor(s2, off);
  }
  __shared__ float red[8];
  if ((t & 63) == 0) { red[t >> 6] = s; red[4 + (t >> 6)] = s2; }
  __syncthreads();
  float S  = red[0] + red[1] + red[2] + red[3];
  float S2 = red[4] + red[5] + red[6] + red[7];
  float mu = S * (1.0f / 2048.0f);
  float var = S2 * (1.0f / 2048.0f) - mu * mu;
  float rstd = rsqrtf(var + 1e-6f);
  const float4* gv = (const float4*)gam;
  const float4* bv = (const float4*)bet;
  float4 g1 = gv[t], g2 = gv[t + 256], c1 = bv[t], c2 = bv[t + 256];
  bf16_t* orow = out + (size_t)row * 2048;
  orow[4*t + 0]    = __float2bfloat16((a.x - mu) * rstd * g1.x + c1.x);
  orow[4*t + 1]    = __float2bfloat16((a.y - mu) * rstd * g1.y + c1.y);
  orow[4*t + 2]    = __float2bfloat16((a.z - mu) * rstd * g1.z + c1.z);
  orow[4*t + 3]    = __float2bfloat16((a.w - mu) * rstd * g1.w + c1.w);
  orow[1024 + 4*t + 0] = __float2bfloat16((b.x - mu) * rstd * g2.x + c2.x);
  orow[1024 + 4*t + 1] = __float2bfloat16((b.y - mu) * rstd * g2.y + c2.y);
  orow[1024 + 4*t + 2] = __float2bfloat16((b.z - mu) * rstd * g2.z + c2.z);
  orow[1024 + 4*t + 3] = __float2bfloat16((b.w - mu) * rstd * g2.w + c2.w);
}

// ---------- 8-phase 256x256 GEMM (R13, best measured): B-frag register retention ----------
// bq0 (n-lo) loaded once in P1 and kept in registers through P4 -> 24 ds_read_b128
// per K-tile per wave, phase 4 read-free. XCD-resident-B mapping.
// EPI: 0 = bf16+bias ; 1 = bf16+bias+gelu ; 3 = f32 atomicAdd (+bias on chunk 0);
//      4 = QKV: n0<4096 -> bf16+bias into Cb; n0>=4096 -> packed vT store only.
template <int EPI>
__global__ __launch_bounds__(512, 2) void k_gemm8(const bf16_t* __restrict__ A,
                                                  const bf16_t* __restrict__ Bt,
                                                  const float* __restrict__ bias,
                                                  bf16_t* __restrict__ Cb,
                                                  float* __restrict__ Cf,
                                                  bf16_t* __restrict__ Vt,
                                                  int Ndim, int LDA, int LDB,
                                                  int Kdim, int nsub) {
  __shared__ __align__(16) char lds[131072];
  int orig = blockIdx.x;
  int xcd = orig & 7;
  int i = orig >> 3;
  int m = i & 15;
  int j = i >> 4;
  int n_local = j % nsub;
  int chunk = j / nsub;
  int m0 = m * 256;
  int n0 = (xcd * nsub + n_local) * 256;
  int tid = threadIdx.x;
  int w = tid >> 6, lane = tid & 63;
  int lr = lane & 15, lk = lane >> 4;
  int wr = w >> 2, wc = w & 3;

  const bf16_t* Ag = A + (size_t)m0 * LDA + (size_t)chunk * Kdim;
  const bf16_t* Bg = Bt + (size_t)n0 * LDB + (size_t)chunk * Kdim;
  int swch = ((tid & 7) ^ ((tid >> 3) & 7)) << 3;
  const bf16_t* pA0 = Ag + (size_t)(tid >> 3) * LDA + swch;
  const bf16_t* pA1 = pA0 + (size_t)128 * LDA;
  int nb0 = ((tid >> 8) & 1) * 64 + ((tid >> 3) & 31);
  const bf16_t* pB0 = Bg + (size_t)nb0 * LDB + swch;
  const bf16_t* pB1 = pB0 + (size_t)128 * LDB;
  int dstb = tid * 16;
  int chv0 = ((lk)     ^ (lr & 7)) * 16;
  int chv1 = ((4 + lk) ^ (lr & 7)) * 16;
  int aof0 = 65536 + wr * 8192 + lr * 128 + chv0;
  int aof1 = 65536 + wr * 8192 + lr * 128 + chv1;
  int bof0 = wc * 4096 + lr * 128 + chv0;
  int bof1 = wc * 4096 + lr * 128 + chv1;

  f32x4 acc[8][4];
#pragma unroll
  for (int ii = 0; ii < 8; ++ii)
#pragma unroll
    for (int jj = 0; jj < 4; ++jj) acc[ii][jj] = (f32x4){0.f, 0.f, 0.f, 0.f};
  short8 af[4][2], bq0[2][2], bq1[2][2];

#define STAGE_A(p, h, kt) do { \
    size_t ko = (size_t)(kt) * 64 + (size_t)(h) * 64 * LDA; \
    gload_lds16(pA0 + ko, lds + 65536 + (p) * 32768 + (h) * 16384 + dstb); \
    gload_lds16(pA1 + ko, lds + 65536 + (p) * 32768 + (h) * 16384 + 8192 + dstb); } while (0)
#define STAGE_B(p, h, kt) do { \
    size_t ko = (size_t)(kt) * 64 + (size_t)(h) * 32 * LDB; \
    gload_lds16(pB0 + ko, lds + (p) * 32768 + (h) * 16384 + dstb); \
    gload_lds16(pB1 + ko, lds + (p) * 32768 + (h) * 16384 + 8192 + dstb); } while (0)
#define READ_A(p, mh) do { \
    _Pragma("unroll") for (int mf = 0; mf < 4; ++mf) { \
      af[mf][0] = *(const short8*)(lds + (p) * 32768 + (mh) * 16384 + mf * 2048 + aof0); \
      af[mf][1] = *(const short8*)(lds + (p) * 32768 + (mh) * 16384 + mf * 2048 + aof1); } } while (0)
#define READ_B0(p) do { \
    _Pragma("unroll") for (int nf = 0; nf < 2; ++nf) { \
      bq0[nf][0] = *(const short8*)(lds + (p) * 32768 + nf * 2048 + bof0); \
      bq0[nf][1] = *(const short8*)(lds + (p) * 32768 + nf * 2048 + bof1); } } while (0)
#define READ_B1(p) do { \
    _Pragma("unroll") for (int nf = 0; nf < 2; ++nf) { \
      bq1[nf][0] = *(const short8*)(lds + (p) * 32768 + 16384 + nf * 2048 + bof0); \
      bq1[nf][1] = *(const short8*)(lds + (p) * 32768 + 16384 + nf * 2048 + bof1); } } while (0)
#define MM16(mh, nh) do { \
    _Pragma("unroll") for (int ks = 0; ks < 2; ++ks) \
    _Pragma("unroll") for (int mf = 0; mf < 4; ++mf) \
    _Pragma("unroll") for (int nf = 0; nf < 2; ++nf) \
      acc[(mh) * 4 + mf][(nh) * 2 + nf] = __builtin_amdgcn_mfma_f32_16x16x32_bf16( \
          af[mf][ks], (nh) ? bq1[nf][ks] : bq0[nf][ks], \
          acc[(mh) * 4 + mf][(nh) * 2 + nf], 0, 0, 0); } while (0)
#define BARRIER() asm volatile("s_barrier" ::: "memory")
#define LGKM0()  do { asm volatile("s_waitcnt lgkmcnt(0)" ::: "memory"); __builtin_amdgcn_sched_barrier(0); } while (0)
#define PRIO1()  __builtin_amdgcn_s_setprio(1)
#define PRIO0()  __builtin_amdgcn_s_setprio(0)
#define BODY(t, p, S1, S2, VMN) do { \
    READ_A(p, 0); READ_B0(p); \
    if (S1) STAGE_B((p) ^ 1, 0, (t) + 1); \
    asm volatile("s_waitcnt lgkmcnt(8)" ::: "memory"); \
    BARRIER(); LGKM0(); PRIO1(); MM16(0, 0); PRIO0(); BARRIER(); \
    READ_B1(p); \
    if (S2) STAGE_A(p, 0, (t) + 2); \
    BARRIER(); LGKM0(); PRIO1(); MM16(0, 1); PRIO0(); BARRIER(); \
    READ_A(p, 1); \
    if (S2) STAGE_B(p, 1, (t) + 2); \
    BARRIER(); LGKM0(); PRIO1(); MM16(1, 1); PRIO0(); BARRIER(); \
    if (S2) STAGE_A(p, 1, (t) + 2); \
    BARRIER(); PRIO1(); MM16(1, 0); PRIO0(); \
    asm volatile("s_waitcnt vmcnt(%0)" :: "i"(VMN) : "memory"); \
    BARRIER(); } while (0)

  const int NT = Kdim >> 6;
  STAGE_A(0, 0, 0); STAGE_B(0, 0, 0); STAGE_B(0, 1, 0); STAGE_A(0, 1, 0);
  STAGE_A(1, 0, 1); STAGE_B(1, 1, 1); STAGE_A(1, 1, 1);
  asm volatile("s_waitcnt vmcnt(6)" ::: "memory");
  BARRIER();

  int t = 0;
  for (; t + 3 < NT; t += 2) {
    BODY(t, 0, 1, 1, 6);
    BODY(t + 1, 1, 1, 1, 6);
  }
  BODY(t, 0, 1, 0, 0);
  {
    READ_A(1, 0); READ_B0(1);
    BARRIER(); LGKM0(); MM16(0, 0); BARRIER();
    READ_B1(1);
    BARRIER(); LGKM0(); MM16(0, 1); BARRIER();
    READ_A(1, 1);
    BARRIER(); LGKM0(); MM16(1, 1); BARRIER();
    MM16(1, 0);
  }
#undef STAGE_A
#undef STAGE_B
#undef READ_A
#undef READ_B0
#undef READ_B1
#undef MM16
#undef BARRIER
#undef LGKM0
#undef PRIO1
#undef PRIO0
#undef BODY

  if (EPI == 4 && n0 >= 4096) {
#pragma unroll
    for (int mf = 0; mf < 8; ++mf) {
#pragma unroll
      for (int nf = 0; nf < 4; ++nf) {
        int cl = n0 + wc * 64 + nf * 16 + lr;
        int d = cl - 4096;
        int hh = d >> 7, dh = d & 127;
        int rwb = m0 + wr * 128 + mf * 16 + lk * 4;
        int bb = rwb >> 11, tt = rwb & 2047;
        float bs = bias[cl];
        short4v s;
#pragma unroll
        for (int r = 0; r < 4; ++r)
          s[r] = (short)__bfloat16_as_ushort(__float2bfloat16(acc[mf][nf][r] + bs));
        *(short4v*)(Vt + ((size_t)(bb * 16 + hh) * 128 + dh) * 2048 + tt) = s;
      }
    }
    return;
  }
#pragma unroll
  for (int mf = 0; mf < 8; ++mf) {
#pragma unroll
    for (int nf = 0; nf < 4; ++nf) {
#pragma unroll
      for (int r = 0; r < 4; ++r) {
        int rw = m0 + wr * 128 + mf * 16 + lk * 4 + r;
        int cl = n0 + wc * 64 + nf * 16 + lr;
        float v = acc[mf][nf][r];
        size_t gi = (size_t)rw * Ndim + cl;
        if (EPI == 0 || EPI == 4) {
          Cb[gi] = __float2bfloat16(v + bias[cl]);
        } else if (EPI == 1) {
          float vv = v + bias[cl];
          float u = vv * (vv * vv * 0.044715f + 1.0f) * 0.7978845608028654f;
          float gl = 0.5f * vv * (1.0f + tanhf(u));
          Cb[gi] = __float2bfloat16(gl);
        } else {
          float add = v + (chunk == 0 ? bias[cl] : 0.0f);
          atomicAdd(&Cf[gi], add);
        }
      }
    }
  }
}

// ---------- causal flash attention + residual add ----------
__global__ __launch_bounds__(256, 2) void k_attn(const bf16_t* __restrict__ qkv,
                                                 const bf16_t* __restrict__ vT,
                                                 const float* __restrict__ x,
                                                 float* __restrict__ out) {
  __shared__ __align__(16) bf16_t Pl[4][32][40];
  int j = blockIdx.x;
  int bh = j & 31;
  int cq = j >> 5;
  int b = bh >> 4, h = bh & 15;
  int w = threadIdx.x >> 6, lane = threadIdx.x & 63;
  int lr = lane & 15, lk = lane >> 4;
  int c = (w == 0) ? cq : (w == 1) ? (63 - cq) : (w == 2) ? (31 - cq) : (32 + cq);
  int q0 = c * 32;
  const bf16_t* qb = qkv + (size_t)(b * 2048) * 6144 + h * 128;
  const bf16_t* kb = qb + 2048;
  const bf16_t* vb = vT + (size_t)(b * 16 + h) * 128 * 2048;
  short8 qf[2][4];
#pragma unroll
  for (int qg = 0; qg < 2; ++qg)
#pragma unroll
    for (int d4 = 0; d4 < 4; ++d4)
      qf[qg][d4] = *(const short8*)(qb + (size_t)(q0 + qg * 16 + lr) * 6144 + d4 * 32 + lk * 8);
  float m[2][4], l[2][4];
#pragma unroll
  for (int qg = 0; qg < 2; ++qg)
#pragma unroll
    for (int r = 0; r < 4; ++r) { m[qg][r] = -1e30f; l[qg][r] = 0.f; }
  f32x4 o[2][8] = {};
  int nkt = c + 1;
  const float sc = 0.08838834764831845f;
  short8 kf[2][4], vf[8];
#pragma unroll
  for (int nt = 0; nt < 2; ++nt)
#pragma unroll
    for (int d4 = 0; d4 < 4; ++d4)
      kf[nt][d4] = *(const short8*)(kb + (size_t)(nt * 16 + lr) * 6144 + d4 * 32 + lk * 8);
#pragma unroll
  for (int d8 = 0; d8 < 8; ++d8)
    vf[d8] = *(const short8*)(vb + (size_t)(d8 * 16 + lr) * 2048 + lk * 8);

  for (int kt = 0; kt < nkt; ++kt) {
    int tk0 = kt * 32;
    f32x4 s[2][2] = {};
    __builtin_amdgcn_s_setprio(1);
#pragma unroll
    for (int d4 = 0; d4 < 4; ++d4)
#pragma unroll
      for (int qg = 0; qg < 2; ++qg)
#pragma unroll
        for (int nt = 0; nt < 2; ++nt)
          s[qg][nt] = __builtin_amdgcn_mfma_f32_16x16x32_bf16(qf[qg][d4], kf[nt][d4], s[qg][nt], 0, 0, 0);
    __builtin_amdgcn_s_setprio(0);
    if (kt + 1 < nkt) {
      int tn = tk0 + 32;
#pragma unroll
      for (int nt = 0; nt < 2; ++nt)
#pragma unroll
        for (int d4 = 0; d4 < 4; ++d4)
          kf[nt][d4] = *(const short8*)(kb + (size_t)(tn + nt * 16 + lr) * 6144 + d4 * 32 + lk * 8);
    }
#pragma unroll
    for (int qg = 0; qg < 2; ++qg) {
      float sv[2][4], mt[4];
#pragma unroll
      for (int r = 0; r < 4; ++r) {
        int qr = q0 + qg * 16 + lk * 4 + r;
#pragma unroll
        for (int nt = 0; nt < 2; ++nt) {
          float v = s[qg][nt][r] * sc;
          int kc = tk0 + nt * 16 + lr;
          sv[nt][r] = (kc > qr) ? -1e30f : v;
        }
        mt[r] = fmaxf(sv[0][r], sv[1][r]);
      }
#pragma unroll
      for (int off = 1; off < 16; off <<= 1)
#pragma unroll
        for (int r = 0; r < 4; ++r) mt[r] = fmaxf(mt[r], __shfl_xor(mt[r], off));
      float alpha[4], rs[4];
#pragma unroll
      for (int r = 0; r < 4; ++r) {
        float mn = fmaxf(m[qg][r], mt[r]);
        alpha[r] = __expf(m[qg][r] - mn);
        m[qg][r] = mn;
      }
#pragma unroll
      for (int r = 0; r < 4; ++r) {
        float p0 = __expf(sv[0][r] - m[qg][r]);
        float p1 = __expf(sv[1][r] - m[qg][r]);
        rs[r] = p0 + p1;
        Pl[w][qg * 16 + lk * 4 + r][lr]      = __float2bfloat16(p0);
        Pl[w][qg * 16 + lk * 4 + r][16 + lr] = __float2bfloat16(p1);
      }
#pragma unroll
      for (int off = 1; off < 16; off <<= 1)
#pragma unroll
        for (int r = 0; r < 4; ++r) rs[r] += __shfl_xor(rs[r], off);
#pragma unroll
      for (int r = 0; r < 4; ++r) l[qg][r] = l[qg][r] * alpha[r] + rs[r];
#pragma unroll
      for (int d8 = 0; d8 < 8; ++d8)
#pragma unroll
        for (int r = 0; r < 4; ++r) o[qg][d8][r] *= alpha[r];
    }
    asm volatile("s_waitcnt lgkmcnt(0)" ::: "memory");
    short8 pf[2];
#pragma unroll
    for (int qg = 0; qg < 2; ++qg)
      pf[qg] = *(const short8*)(&Pl[w][qg * 16 + lr][lk * 8]);
    __builtin_amdgcn_s_setprio(1);
#pragma unroll
    for (int d8 = 0; d8 < 8; ++d8)
#pragma unroll
      for (int qg = 0; qg < 2; ++qg)
        o[qg][d8] = __builtin_amdgcn_mfma_f32_16x16x32_bf16(pf[qg], vf[d8], o[qg][d8], 0, 0, 0);
    __builtin_amdgcn_s_setprio(0);
    if (kt + 1 < nkt) {
      int tn = tk0 + 32;
#pragma unroll
      for (int d8 = 0; d8 < 8; ++d8)
        vf[d8] = *(const short8*)(vb + (size_t)(d8 * 16 + lr) * 2048 + tn + lk * 8);
    }
  }
#pragma unroll
  for (int qg = 0; qg < 2; ++qg)
#pragma unroll
    for (int d8 = 0; d8 < 8; ++d8)
#pragma unroll
      for (int r = 0; r < 4; ++r) {
        int qr = q0 + qg * 16 + lk * 4 + r;
        int cl = h * 128 + d8 * 16 + lr;
        size_t gi = (size_t)(b * 2048 + qr) * 2048 + cl;
        out[gi] = x[gi] + o[qg][d8][r] / l[qg][r];
      }
}

extern "C" void kernel_launch(void* const* d_in, const int* in_sizes, int n_in,
                              void* d_out, int out_size, void* d_ws, size_t ws_size,
                              hipStream_t stream) {
  const float* x    = (const float*)d_in[0];
  const float* ln1s = (const float*)d_in[1];
  const float* ln1b = (const float*)d_in[2];
  const float* wqkv = (const float*)d_in[3];
  const float* bqkv = (const float*)d_in[4];
  const float* ln2s = (const float*)d_in[5];
  const float* ln2b = (const float*)d_in[6];
  const float* w1   = (const float*)d_in[7];
  const float* b1   = (const float*)d_in[8];
  const float* w2   = (const float*)d_in[9];
  const float* b2   = (const float*)d_in[10];
  float* out = (float*)d_out;
  char* ws = (char*)d_ws;

  // ws layout (bytes): r@0 16MB; qkv@16MB 48MB (V third unused); w1T@64MB 32MB;
  // w2T@96MB 32MB; h@128MB 64MB (clobbers wqkvT+vT after attention);
  // wqkvT@128MB 24MB (dead before h); vT@160MB 16MB (dead before h).
  bf16_t* r     = (bf16_t*)(ws + 0);
  bf16_t* qkv   = (bf16_t*)(ws + 16777216);
  bf16_t* w1T   = (bf16_t*)(ws + 67108864);
  bf16_t* w2T   = (bf16_t*)(ws + 100663296);
  bf16_t* h     = (bf16_t*)(ws + 134217728);
  bf16_t* wqkvT = (bf16_t*)(ws + 134217728);
  bf16_t* vT    = (bf16_t*)(ws + 167772160);

  // weight transposes (f32 [K][N] -> bf16 [N][K])
  k_transpose_cvt<<<dim3(96, 32),  256, 0, stream>>>(wqkv, wqkvT, 2048, 6144);
  k_transpose_cvt<<<dim3(128, 32), 256, 0, stream>>>(w1,   w1T,   2048, 8192);
  k_transpose_cvt<<<dim3(32, 128), 256, 0, stream>>>(w2,   w2T,   8192, 2048);
  // LN1
  k_layernorm<<<4096, 256, 0, stream>>>(x, ln1s, ln1b, r);
  // QKV (fused V-transpose): 24 n-tiles, nsub=3; 384 blocks
  k_gemm8<4><<<384, 512, 0, stream>>>(r, wqkvT, bqkv, qkv, nullptr, vT, 6144, 2048, 2048, 2048, 3);
  // attention + residual (writes every element of d_out)
  k_attn<<<512, 256, 0, stream>>>(qkv, vT, x, out);
  // LN2 on x2 = d_out
  k_layernorm<<<4096, 256, 0, stream>>>(out, ln2s, ln2b, r);
  // MLP1: 32 n-tiles, nsub=4; 512 blocks
  k_gemm8<1><<<512, 512, 0, stream>>>(r, w1T, b1, h, nullptr, nullptr, 8192, 2048, 2048, 2048, 4);
  // MLP2 split-K=2, atomicAdd epilogue: nsub=1; 256 blocks
  k_gemm8<3><<<256, 512, 0, stream>>>(h, w2T, b2, nullptr, out, nullptr, 2048, 8192, 8192, 4096, 1);
}

// Round 16
// 636.670 us; speedup vs baseline: 1.6067x; 1.0167x over previous
//
#include <hip/hip_runtime.h>
#include <hip/hip_bf16.h>
#include <stdint.h>
#include <stddef.h>

// B=2, T=2048, D=2048, H=16, DH=128, F=8192, M=B*T=4096
using bf16_t = __hip_bfloat16;
typedef __attribute__((ext_vector_type(8))) short short8;
typedef __attribute__((ext_vector_type(4))) short short4v;
typedef __attribute__((ext_vector_type(4))) float f32x4;

__device__ __forceinline__ void gload_lds16(const void* g, void* l) {
  __builtin_amdgcn_global_load_lds((const __attribute__((address_space(1))) void*)g,
                                   (__attribute__((address_space(3))) void*)l,
                                   16, 0, 0);
}

// ---------- transpose + f32->bf16 convert: out[N][K] = in[K][N] ----------
__global__ __launch_bounds__(256) void k_transpose_cvt(const float* __restrict__ in,
                                                       bf16_t* __restrict__ out,
                                                       int K, int N) {
  __shared__ float tile[64][65];
  int n0 = blockIdx.x * 64, k0 = blockIdx.y * 64;
  int t = threadIdx.x;
  int tr = t >> 4, tc = t & 15;
#pragma unroll
  for (int i = 0; i < 4; ++i) {
    float4 v = *(const float4*)(in + (size_t)(k0 + tr + i * 16) * N + n0 + tc * 4);
    tile[tr + i * 16][tc * 4 + 0] = v.x;
    tile[tr + i * 16][tc * 4 + 1] = v.y;
    tile[tr + i * 16][tc * 4 + 2] = v.z;
    tile[tr + i * 16][tc * 4 + 3] = v.w;
  }
  __syncthreads();
#pragma unroll
  for (int i = 0; i < 4; ++i) {
    int nn = tr + i * 16;
    short4v s;
    s[0] = (short)__bfloat16_as_ushort(__float2bfloat16(tile[tc * 4 + 0][nn]));
    s[1] = (short)__bfloat16_as_ushort(__float2bfloat16(tile[tc * 4 + 1][nn]));
    s[2] = (short)__bfloat16_as_ushort(__float2bfloat16(tile[tc * 4 + 2][nn]));
    s[3] = (short)__bfloat16_as_ushort(__float2bfloat16(tile[tc * 4 + 3][nn]));
    *(short4v*)(out + (size_t)(n0 + nn) * K + k0 + tc * 4) = s;
  }
}

// ---------- layernorm f32 -> bf16, one block per row of 2048 ----------
__global__ __launch_bounds__(256) void k_layernorm(const float* __restrict__ x,
                                                   const float* __restrict__ gam,
                                                   const float* __restrict__ bet,
                                                   bf16_t* __restrict__ out) {
  int row = blockIdx.x, t = threadIdx.x;
  const float4* xr = (const float4*)(x + (size_t)row * 2048);
  float4 a = xr[t], b = xr[t + 256];
  float s  = a.x + a.y + a.z + a.w + b.x + b.y + b.z + b.w;
  float s2 = a.x*a.x + a.y*a.y + a.z*a.z + a.w*a.w
           + b.x*b.x + b.y*b.y + b.z*b.z + b.w*b.w;
#pragma unroll
  for (int off = 32; off >= 1; off >>= 1) {
    s  += __shfl_xor(s, off);
    s2 += __shfl_xor(s2, off);
  }
  __shared__ float red[8];
  if ((t & 63) == 0) { red[t >> 6] = s; red[4 + (t >> 6)] = s2; }
  __syncthreads();
  float S  = red[0] + red[1] + red[2] + red[3];
  float S2 = red[4] + red[5] + red[6] + red[7];
  float mu = S * (1.0f / 2048.0f);
  float var = S2 * (1.0f / 2048.0f) - mu * mu;
  float rstd = rsqrtf(var + 1e-6f);
  const float4* gv = (const float4*)gam;
  const float4* bv = (const float4*)bet;
  float4 g1 = gv[t], g2 = gv[t + 256], c1 = bv[t], c2 = bv[t + 256];
  bf16_t* orow = out + (size_t)row * 2048;
  orow[4*t + 0]    = __float2bfloat16((a.x - mu) * rstd * g1.x + c1.x);
  orow[4*t + 1]    = __float2bfloat16((a.y - mu) * rstd * g1.y + c1.y);
  orow[4*t + 2]    = __float2bfloat16((a.z - mu) * rstd * g1.z + c1.z);
  orow[4*t + 3]    = __float2bfloat16((a.w - mu) * rstd * g1.w + c1.w);
  orow[1024 + 4*t + 0] = __float2bfloat16((b.x - mu) * rstd * g2.x + c2.x);
  orow[1024 + 4*t + 1] = __float2bfloat16((b.y - mu) * rstd * g2.y + c2.y);
  orow[1024 + 4*t + 2] = __float2bfloat16((b.z - mu) * rstd * g2.z + c2.z);
  orow[1024 + 4*t + 3] = __float2bfloat16((b.w - mu) * rstd * g2.w + c2.w);
}

// ---------- 8-phase 256x256 GEMM (R13/R15, best measured) ----------
// EPI: 0 = bf16+bias ; 1 = bf16+bias+gelu ; 3 = f32 atomicAdd (+bias on chunk 0);
//      4 = QKV: n0<4096 -> bf16+bias into Cb; n0>=4096 -> packed vT store only.
template <int EPI>
__global__ __launch_bounds__(512, 2) void k_gemm8(const bf16_t* __restrict__ A,
                                                  const bf16_t* __restrict__ Bt,
                                                  const float* __restrict__ bias,
                                                  bf16_t* __restrict__ Cb,
                                                  float* __restrict__ Cf,
                                                  bf16_t* __restrict__ Vt,
                                                  int Ndim, int LDA, int LDB,
                                                  int Kdim, int nsub) {
  __shared__ __align__(16) char lds[131072];
  int orig = blockIdx.x;
  int xcd = orig & 7;
  int i = orig >> 3;
  int m = i & 15;
  int j = i >> 4;
  int n_local = j % nsub;
  int chunk = j / nsub;
  int m0 = m * 256;
  int n0 = (xcd * nsub + n_local) * 256;
  int tid = threadIdx.x;
  int w = tid >> 6, lane = tid & 63;
  int lr = lane & 15, lk = lane >> 4;
  int wr = w >> 2, wc = w & 3;

  const bf16_t* Ag = A + (size_t)m0 * LDA + (size_t)chunk * Kdim;
  const bf16_t* Bg = Bt + (size_t)n0 * LDB + (size_t)chunk * Kdim;
  int swch = ((tid & 7) ^ ((tid >> 3) & 7)) << 3;
  const bf16_t* pA0 = Ag + (size_t)(tid >> 3) * LDA + swch;
  const bf16_t* pA1 = pA0 + (size_t)128 * LDA;
  int nb0 = ((tid >> 8) & 1) * 64 + ((tid >> 3) & 31);
  const bf16_t* pB0 = Bg + (size_t)nb0 * LDB + swch;
  const bf16_t* pB1 = pB0 + (size_t)128 * LDB;
  int dstb = tid * 16;
  int chv0 = ((lk)     ^ (lr & 7)) * 16;
  int chv1 = ((4 + lk) ^ (lr & 7)) * 16;
  int aof0 = 65536 + wr * 8192 + lr * 128 + chv0;
  int aof1 = 65536 + wr * 8192 + lr * 128 + chv1;
  int bof0 = wc * 4096 + lr * 128 + chv0;
  int bof1 = wc * 4096 + lr * 128 + chv1;

  f32x4 acc[8][4];
#pragma unroll
  for (int ii = 0; ii < 8; ++ii)
#pragma unroll
    for (int jj = 0; jj < 4; ++jj) acc[ii][jj] = (f32x4){0.f, 0.f, 0.f, 0.f};
  short8 af[4][2], bq0[2][2], bq1[2][2];

#define STAGE_A(p, h, kt) do { \
    size_t ko = (size_t)(kt) * 64 + (size_t)(h) * 64 * LDA; \
    gload_lds16(pA0 + ko, lds + 65536 + (p) * 32768 + (h) * 16384 + dstb); \
    gload_lds16(pA1 + ko, lds + 65536 + (p) * 32768 + (h) * 16384 + 8192 + dstb); } while (0)
#define STAGE_B(p, h, kt) do { \
    size_t ko = (size_t)(kt) * 64 + (size_t)(h) * 32 * LDB; \
    gload_lds16(pB0 + ko, lds + (p) * 32768 + (h) * 16384 + dstb); \
    gload_lds16(pB1 + ko, lds + (p) * 32768 + (h) * 16384 + 8192 + dstb); } while (0)
#define READ_A(p, mh) do { \
    _Pragma("unroll") for (int mf = 0; mf < 4; ++mf) { \
      af[mf][0] = *(const short8*)(lds + (p) * 32768 + (mh) * 16384 + mf * 2048 + aof0); \
      af[mf][1] = *(const short8*)(lds + (p) * 32768 + (mh) * 16384 + mf * 2048 + aof1); } } while (0)
#define READ_B0(p) do { \
    _Pragma("unroll") for (int nf = 0; nf < 2; ++nf) { \
      bq0[nf][0] = *(const short8*)(lds + (p) * 32768 + nf * 2048 + bof0); \
      bq0[nf][1] = *(const short8*)(lds + (p) * 32768 + nf * 2048 + bof1); } } while (0)
#define READ_B1(p) do { \
    _Pragma("unroll") for (int nf = 0; nf < 2; ++nf) { \
      bq1[nf][0] = *(const short8*)(lds + (p) * 32768 + 16384 + nf * 2048 + bof0); \
      bq1[nf][1] = *(const short8*)(lds + (p) * 32768 + 16384 + nf * 2048 + bof1); } } while (0)
#define MM16(mh, nh) do { \
    _Pragma("unroll") for (int ks = 0; ks < 2; ++ks) \
    _Pragma("unroll") for (int mf = 0; mf < 4; ++mf) \
    _Pragma("unroll") for (int nf = 0; nf < 2; ++nf) \
      acc[(mh) * 4 + mf][(nh) * 2 + nf] = __builtin_amdgcn_mfma_f32_16x16x32_bf16( \
          af[mf][ks], (nh) ? bq1[nf][ks] : bq0[nf][ks], \
          acc[(mh) * 4 + mf][(nh) * 2 + nf], 0, 0, 0); } while (0)
#define BARRIER() asm volatile("s_barrier" ::: "memory")
#define LGKM0()  do { asm volatile("s_waitcnt lgkmcnt(0)" ::: "memory"); __builtin_amdgcn_sched_barrier(0); } while (0)
#define PRIO1()  __builtin_amdgcn_s_setprio(1)
#define PRIO0()  __builtin_amdgcn_s_setprio(0)
#define BODY(t, p, S1, S2, VMN) do { \
    READ_A(p, 0); READ_B0(p); \
    if (S1) STAGE_B((p) ^ 1, 0, (t) + 1); \
    asm volatile("s_waitcnt lgkmcnt(8)" ::: "memory"); \
    BARRIER(); LGKM0(); PRIO1(); MM16(0, 0); PRIO0(); BARRIER(); \
    READ_B1(p); \
    if (S2) STAGE_A(p, 0, (t) + 2); \
    BARRIER(); LGKM0(); PRIO1(); MM16(0, 1); PRIO0(); BARRIER(); \
    READ_A(p, 1); \
    if (S2) STAGE_B(p, 1, (t) + 2); \
    BARRIER(); LGKM0(); PRIO1(); MM16(1, 1); PRIO0(); BARRIER(); \
    if (S2) STAGE_A(p, 1, (t) + 2); \
    BARRIER(); PRIO1(); MM16(1, 0); PRIO0(); \
    asm volatile("s_waitcnt vmcnt(%0)" :: "i"(VMN) : "memory"); \
    BARRIER(); } while (0)

  const int NT = Kdim >> 6;
  STAGE_A(0, 0, 0); STAGE_B(0, 0, 0); STAGE_B(0, 1, 0); STAGE_A(0, 1, 0);
  STAGE_A(1, 0, 1); STAGE_B(1, 1, 1); STAGE_A(1, 1, 1);
  asm volatile("s_waitcnt vmcnt(6)" ::: "memory");
  BARRIER();

  int t = 0;
  for (; t + 3 < NT; t += 2) {
    BODY(t, 0, 1, 1, 6);
    BODY(t + 1, 1, 1, 1, 6);
  }
  BODY(t, 0, 1, 0, 0);
  {
    READ_A(1, 0); READ_B0(1);
    BARRIER(); LGKM0(); MM16(0, 0); BARRIER();
    READ_B1(1);
    BARRIER(); LGKM0(); MM16(0, 1); BARRIER();
    READ_A(1, 1);
    BARRIER(); LGKM0(); MM16(1, 1); BARRIER();
    MM16(1, 0);
  }
#undef STAGE_A
#undef STAGE_B
#undef READ_A
#undef READ_B0
#undef READ_B1
#undef MM16
#undef BARRIER
#undef LGKM0
#undef PRIO1
#undef PRIO0
#undef BODY

  if (EPI == 4 && n0 >= 4096) {
#pragma unroll
    for (int mf = 0; mf < 8; ++mf) {
#pragma unroll
      for (int nf = 0; nf < 4; ++nf) {
        int cl = n0 + wc * 64 + nf * 16 + lr;
        int d = cl - 4096;
        int hh = d >> 7, dh = d & 127;
        int rwb = m0 + wr * 128 + mf * 16 + lk * 4;
        int bb = rwb >> 11, tt = rwb & 2047;
        float bs = bias[cl];
        short4v s;
#pragma unroll
        for (int r = 0; r < 4; ++r)
          s[r] = (short)__bfloat16_as_ushort(__float2bfloat16(acc[mf][nf][r] + bs));
        *(short4v*)(Vt + ((size_t)(bb * 16 + hh) * 128 + dh) * 2048 + tt) = s;
      }
    }
    return;
  }
#pragma unroll
  for (int mf = 0; mf < 8; ++mf) {
#pragma unroll
    for (int nf = 0; nf < 4; ++nf) {
#pragma unroll
      for (int r = 0; r < 4; ++r) {
        int rw = m0 + wr * 128 + mf * 16 + lk * 4 + r;
        int cl = n0 + wc * 64 + nf * 16 + lr;
        float v = acc[mf][nf][r];
        size_t gi = (size_t)rw * Ndim + cl;
        if (EPI == 0 || EPI == 4) {
          Cb[gi] = __float2bfloat16(v + bias[cl]);
        } else if (EPI == 1) {
          float vv = v + bias[cl];
          float u = vv * (vv * vv * 0.044715f + 1.0f) * 0.7978845608028654f;
          float gl = 0.5f * vv * (1.0f + tanhf(u));
          Cb[gi] = __float2bfloat16(gl);
        } else {
          float add = v + (chunk == 0 ? bias[cl] : 0.0f);
          atomicAdd(&Cf[gi], add);
        }
      }
    }
  }
}

// ---------- causal flash attention + residual add ----------
// R16: T13 defer-max — skip the max-reduce + alpha-rescale when the tile's
// per-lane max stays within THR=8 of the running max (__all -> wave-uniform
// branch). P bounded by e^8, o/l ratio exact. First tile always full path.
__global__ __launch_bounds__(256, 2) void k_attn(const bf16_t* __restrict__ qkv,
                                                 const bf16_t* __restrict__ vT,
                                                 const float* __restrict__ x,
                                                 float* __restrict__ out) {
  __shared__ __align__(16) bf16_t Pl[4][32][40];
  int j = blockIdx.x;
  int bh = j & 31;
  int cq = j >> 5;
  int b = bh >> 4, h = bh & 15;
  int w = threadIdx.x >> 6, lane = threadIdx.x & 63;
  int lr = lane & 15, lk = lane >> 4;
  int c = (w == 0) ? cq : (w == 1) ? (63 - cq) : (w == 2) ? (31 - cq) : (32 + cq);
  int q0 = c * 32;
  const bf16_t* qb = qkv + (size_t)(b * 2048) * 6144 + h * 128;
  const bf16_t* kb = qb + 2048;
  const bf16_t* vb = vT + (size_t)(b * 16 + h) * 128 * 2048;
  short8 qf[2][4];
#pragma unroll
  for (int qg = 0; qg < 2; ++qg)
#pragma unroll
    for (int d4 = 0; d4 < 4; ++d4)
      qf[qg][d4] = *(const short8*)(qb + (size_t)(q0 + qg * 16 + lr) * 6144 + d4 * 32 + lk * 8);
  float m[2][4], l[2][4];
#pragma unroll
  for (int qg = 0; qg < 2; ++qg)
#pragma unroll
    for (int r = 0; r < 4; ++r) { m[qg][r] = -1e30f; l[qg][r] = 0.f; }
  f32x4 o[2][8] = {};
  int nkt = c + 1;
  const float sc = 0.08838834764831845f;
  short8 kf[2][4], vf[8];
#pragma unroll
  for (int nt = 0; nt < 2; ++nt)
#pragma unroll
    for (int d4 = 0; d4 < 4; ++d4)
      kf[nt][d4] = *(const short8*)(kb + (size_t)(nt * 16 + lr) * 6144 + d4 * 32 + lk * 8);
#pragma unroll
  for (int d8 = 0; d8 < 8; ++d8)
    vf[d8] = *(const short8*)(vb + (size_t)(d8 * 16 + lr) * 2048 + lk * 8);

  for (int kt = 0; kt < nkt; ++kt) {
    int tk0 = kt * 32;
    f32x4 s[2][2] = {};
    __builtin_amdgcn_s_setprio(1);
#pragma unroll
    for (int d4 = 0; d4 < 4; ++d4)
#pragma unroll
      for (int qg = 0; qg < 2; ++qg)
#pragma unroll
        for (int nt = 0; nt < 2; ++nt)
          s[qg][nt] = __builtin_amdgcn_mfma_f32_16x16x32_bf16(qf[qg][d4], kf[nt][d4], s[qg][nt], 0, 0, 0);
    __builtin_amdgcn_s_setprio(0);
    if (kt + 1 < nkt) {
      int tn = tk0 + 32;
#pragma unroll
      for (int nt = 0; nt < 2; ++nt)
#pragma unroll
        for (int d4 = 0; d4 < 4; ++d4)
          kf[nt][d4] = *(const short8*)(kb + (size_t)(tn + nt * 16 + lr) * 6144 + d4 * 32 + lk * 8);
    }
#pragma unroll
    for (int qg = 0; qg < 2; ++qg) {
      float sv[2][4], mt[4];
#pragma unroll
      for (int r = 0; r < 4; ++r) {
        int qr = q0 + qg * 16 + lk * 4 + r;
#pragma unroll
        for (int nt = 0; nt < 2; ++nt) {
          float v = s[qg][nt][r] * sc;
          int kc = tk0 + nt * 16 + lr;
          sv[nt][r] = (kc > qr) ? -1e30f : v;
        }
        mt[r] = fmaxf(sv[0][r], sv[1][r]);
      }
      // T13 defer-max: only pay the reduce + rescale when the max moved > 8.
      bool ok = true;
#pragma unroll
      for (int r = 0; r < 4; ++r) ok = ok && (mt[r] <= m[qg][r] + 8.0f);
      if (!__all(ok)) {
#pragma unroll
        for (int off = 1; off < 16; off <<= 1)
#pragma unroll
          for (int r = 0; r < 4; ++r) mt[r] = fmaxf(mt[r], __shfl_xor(mt[r], off));
        float alpha[4];
#pragma unroll
        for (int r = 0; r < 4; ++r) {
          float mn = fmaxf(m[qg][r], mt[r]);
          alpha[r] = __expf(m[qg][r] - mn);
          m[qg][r] = mn;
          l[qg][r] *= alpha[r];
        }
#pragma unroll
        for (int d8 = 0; d8 < 8; ++d8)
#pragma unroll
          for (int r = 0; r < 4; ++r) o[qg][d8][r] *= alpha[r];
      }
      float rs[4];
#pragma unroll
      for (int r = 0; r < 4; ++r) {
        float p0 = __expf(sv[0][r] - m[qg][r]);
        float p1 = __expf(sv[1][r] - m[qg][r]);
        rs[r] = p0 + p1;
        Pl[w][qg * 16 + lk * 4 + r][lr]      = __float2bfloat16(p0);
        Pl[w][qg * 16 + lk * 4 + r][16 + lr] = __float2bfloat16(p1);
      }
#pragma unroll
      for (int off = 1; off < 16; off <<= 1)
#pragma unroll
        for (int r = 0; r < 4; ++r) rs[r] += __shfl_xor(rs[r], off);
#pragma unroll
      for (int r = 0; r < 4; ++r) l[qg][r] += rs[r];
    }
    asm volatile("s_waitcnt lgkmcnt(0)" ::: "memory");
    short8 pf[2];
#pragma unroll
    for (int qg = 0; qg < 2; ++qg)
      pf[qg] = *(const short8*)(&Pl[w][qg * 16 + lr][lk * 8]);
    __builtin_amdgcn_s_setprio(1);
#pragma unroll
    for (int d8 = 0; d8 < 8; ++d8)
#pragma unroll
      for (int qg = 0; qg < 2; ++qg)
        o[qg][d8] = __builtin_amdgcn_mfma_f32_16x16x32_bf16(pf[qg], vf[d8], o[qg][d8], 0, 0, 0);
    __builtin_amdgcn_s_setprio(0);
    if (kt + 1 < nkt) {
      int tn = tk0 + 32;
#pragma unroll
      for (int d8 = 0; d8 < 8; ++d8)
        vf[d8] = *(const short8*)(vb + (size_t)(d8 * 16 + lr) * 2048 + tn + lk * 8);
    }
  }
#pragma unroll
  for (int qg = 0; qg < 2; ++qg)
#pragma unroll
    for (int d8 = 0; d8 < 8; ++d8)
#pragma unroll
      for (int r = 0; r < 4; ++r) {
        int qr = q0 + qg * 16 + lk * 4 + r;
        int cl = h * 128 + d8 * 16 + lr;
        size_t gi = (size_t)(b * 2048 + qr) * 2048 + cl;
        out[gi] = x[gi] + o[qg][d8][r] / l[qg][r];
      }
}

extern "C" void kernel_launch(void* const* d_in, const int* in_sizes, int n_in,
                              void* d_out, int out_size, void* d_ws, size_t ws_size,
                              hipStream_t stream) {
  const float* x    = (const float*)d_in[0];
  const float* ln1s = (const float*)d_in[1];
  const float* ln1b = (const float*)d_in[2];
  const float* wqkv = (const float*)d_in[3];
  const float* bqkv = (const float*)d_in[4];
  const float* ln2s = (const float*)d_in[5];
  const float* ln2b = (const float*)d_in[6];
  const float* w1   = (const float*)d_in[7];
  const float* b1   = (const float*)d_in[8];
  const float* w2   = (const float*)d_in[9];
  const float* b2   = (const float*)d_in[10];
  float* out = (float*)d_out;
  char* ws = (char*)d_ws;

  // ws layout (bytes): r@0 16MB; qkv@16MB 48MB (V third unused); w1T@64MB 32MB;
  // w2T@96MB 32MB; h@128MB 64MB (clobbers wqkvT+vT after attention);
  // wqkvT@128MB 24MB (dead before h); vT@160MB 16MB (dead before h).
  bf16_t* r     = (bf16_t*)(ws + 0);
  bf16_t* qkv   = (bf16_t*)(ws + 16777216);
  bf16_t* w1T   = (bf16_t*)(ws + 67108864);
  bf16_t* w2T   = (bf16_t*)(ws + 100663296);
  bf16_t* h     = (bf16_t*)(ws + 134217728);
  bf16_t* wqkvT = (bf16_t*)(ws + 134217728);
  bf16_t* vT    = (bf16_t*)(ws + 167772160);

  // weight transposes (f32 [K][N] -> bf16 [N][K])
  k_transpose_cvt<<<dim3(96, 32),  256, 0, stream>>>(wqkv, wqkvT, 2048, 6144);
  k_transpose_cvt<<<dim3(128, 32), 256, 0, stream>>>(w1,   w1T,   2048, 8192);
  k_transpose_cvt<<<dim3(32, 128), 256, 0, stream>>>(w2,   w2T,   8192, 2048);
  // LN1
  k_layernorm<<<4096, 256, 0, stream>>>(x, ln1s, ln1b, r);
  // QKV (fused V-transpose): 24 n-tiles, nsub=3; 384 blocks
  k_gemm8<4><<<384, 512, 0, stream>>>(r, wqkvT, bqkv, qkv, nullptr, vT, 6144, 2048, 2048, 2048, 3);
  // attention + residual (writes every element of d_out)
  k_attn<<<512, 256, 0, stream>>>(qkv, vT, x, out);
  // LN2 on x2 = d_out
  k_layernorm<<<4096, 256, 0, stream>>>(out, ln2s, ln2b, r);
  // MLP1: 32 n-tiles, nsub=4; 512 blocks
  k_gemm8<1><<<512, 512, 0, stream>>>(r, w1T, b1, h, nullptr, nullptr, 8192, 2048, 2048, 2048, 4);
  // MLP2 split-K=2, atomicAdd epilogue: nsub=1; 256 blocks
  k_gemm8<3><<<256, 512, 0, stream>>>(h, w2T, b2, nullptr, out, nullptr, 2048, 8192, 8192, 4096, 1);
}

// Round 17
// 614.675 us; speedup vs baseline: 1.6642x; 1.0358x over previous
//
#include <hip/hip_runtime.h>
#include <hip/hip_bf16.h>
#include <stdint.h>
#include <stddef.h>

// B=2, T=2048, D=2048, H=16, DH=128, F=8192, M=B*T=4096
using bf16_t = __hip_bfloat16;
typedef __attribute__((ext_vector_type(8))) short short8;
typedef __attribute__((ext_vector_type(4))) short short4v;
typedef __attribute__((ext_vector_type(4))) float f32x4;

__device__ __forceinline__ void gload_lds16(const void* g, void* l) {
  __builtin_amdgcn_global_load_lds((const __attribute__((address_space(1))) void*)g,
                                   (__attribute__((address_space(3))) void*)l,
                                   16, 0, 0);
}

// ---------- transpose + f32->bf16 convert: out[N][K] = in[K][N] ----------
__global__ __launch_bounds__(256) void k_transpose_cvt(const float* __restrict__ in,
                                                       bf16_t* __restrict__ out,
                                                       int K, int N) {
  __shared__ float tile[64][65];
  int n0 = blockIdx.x * 64, k0 = blockIdx.y * 64;
  int t = threadIdx.x;
  int tr = t >> 4, tc = t & 15;
#pragma unroll
  for (int i = 0; i < 4; ++i) {
    float4 v = *(const float4*)(in + (size_t)(k0 + tr + i * 16) * N + n0 + tc * 4);
    tile[tr + i * 16][tc * 4 + 0] = v.x;
    tile[tr + i * 16][tc * 4 + 1] = v.y;
    tile[tr + i * 16][tc * 4 + 2] = v.z;
    tile[tr + i * 16][tc * 4 + 3] = v.w;
  }
  __syncthreads();
#pragma unroll
  for (int i = 0; i < 4; ++i) {
    int nn = tr + i * 16;
    short4v s;
    s[0] = (short)__bfloat16_as_ushort(__float2bfloat16(tile[tc * 4 + 0][nn]));
    s[1] = (short)__bfloat16_as_ushort(__float2bfloat16(tile[tc * 4 + 1][nn]));
    s[2] = (short)__bfloat16_as_ushort(__float2bfloat16(tile[tc * 4 + 2][nn]));
    s[3] = (short)__bfloat16_as_ushort(__float2bfloat16(tile[tc * 4 + 3][nn]));
    *(short4v*)(out + (size_t)(n0 + nn) * K + k0 + tc * 4) = s;
  }
}

// ---------- layernorm f32 -> bf16, one block per row of 2048 ----------
__global__ __launch_bounds__(256) void k_layernorm(const float* __restrict__ x,
                                                   const float* __restrict__ gam,
                                                   const float* __restrict__ bet,
                                                   bf16_t* __restrict__ out) {
  int row = blockIdx.x, t = threadIdx.x;
  const float4* xr = (const float4*)(x + (size_t)row * 2048);
  float4 a = xr[t], b = xr[t + 256];
  float s  = a.x + a.y + a.z + a.w + b.x + b.y + b.z + b.w;
  float s2 = a.x*a.x + a.y*a.y + a.z*a.z + a.w*a.w
           + b.x*b.x + b.y*b.y + b.z*b.z + b.w*b.w;
#pragma unroll
  for (int off = 32; off >= 1; off >>= 1) {
    s  += __shfl_xor(s, off);
    s2 += __shfl_xor(s2, off);
  }
  __shared__ float red[8];
  if ((t & 63) == 0) { red[t >> 6] = s; red[4 + (t >> 6)] = s2; }
  __syncthreads();
  float S  = red[0] + red[1] + red[2] + red[3];
  float S2 = red[4] + red[5] + red[6] + red[7];
  float mu = S * (1.0f / 2048.0f);
  float var = S2 * (1.0f / 2048.0f) - mu * mu;
  float rstd = rsqrtf(var + 1e-6f);
  const float4* gv = (const float4*)gam;
  const float4* bv = (const float4*)bet;
  float4 g1 = gv[t], g2 = gv[t + 256], c1 = bv[t], c2 = bv[t + 256];
  bf16_t* orow = out + (size_t)row * 2048;
  orow[4*t + 0]    = __float2bfloat16((a.x - mu) * rstd * g1.x + c1.x);
  orow[4*t + 1]    = __float2bfloat16((a.y - mu) * rstd * g1.y + c1.y);
  orow[4*t + 2]    = __float2bfloat16((a.z - mu) * rstd * g1.z + c1.z);
  orow[4*t + 3]    = __float2bfloat16((a.w - mu) * rstd * g1.w + c1.w);
  orow[1024 + 4*t + 0] = __float2bfloat16((b.x - mu) * rstd * g2.x + c2.x);
  orow[1024 + 4*t + 1] = __float2bfloat16((b.y - mu) * rstd * g2.y + c2.y);
  orow[1024 + 4*t + 2] = __float2bfloat16((b.z - mu) * rstd * g2.z + c2.z);
  orow[1024 + 4*t + 3] = __float2bfloat16((b.w - mu) * rstd * g2.w + c2.w);
}

// ---------- 8-phase 256x256 GEMM (R13/R15, best measured) ----------
// EPI: 0 = bf16+bias ; 1 = bf16+bias+gelu(exp-form) ; 3 = f32 atomicAdd (+bias on
// chunk 0); 4 = QKV: n0<4096 -> bf16+bias; n0>=4096 -> packed vT store only.
template <int EPI>
__global__ __launch_bounds__(512, 2) void k_gemm8(const bf16_t* __restrict__ A,
                                                  const bf16_t* __restrict__ Bt,
                                                  const float* __restrict__ bias,
                                                  bf16_t* __restrict__ Cb,
                                                  float* __restrict__ Cf,
                                                  bf16_t* __restrict__ Vt,
                                                  int Ndim, int LDA, int LDB,
                                                  int Kdim, int nsub) {
  __shared__ __align__(16) char lds[131072];
  int orig = blockIdx.x;
  int xcd = orig & 7;
  int i = orig >> 3;
  int m = i & 15;
  int j = i >> 4;
  int n_local = j % nsub;
  int chunk = j / nsub;
  int m0 = m * 256;
  int n0 = (xcd * nsub + n_local) * 256;
  int tid = threadIdx.x;
  int w = tid >> 6, lane = tid & 63;
  int lr = lane & 15, lk = lane >> 4;
  int wr = w >> 2, wc = w & 3;

  const bf16_t* Ag = A + (size_t)m0 * LDA + (size_t)chunk * Kdim;
  const bf16_t* Bg = Bt + (size_t)n0 * LDB + (size_t)chunk * Kdim;
  int swch = ((tid & 7) ^ ((tid >> 3) & 7)) << 3;
  const bf16_t* pA0 = Ag + (size_t)(tid >> 3) * LDA + swch;
  const bf16_t* pA1 = pA0 + (size_t)128 * LDA;
  int nb0 = ((tid >> 8) & 1) * 64 + ((tid >> 3) & 31);
  const bf16_t* pB0 = Bg + (size_t)nb0 * LDB + swch;
  const bf16_t* pB1 = pB0 + (size_t)128 * LDB;
  int dstb = tid * 16;
  int chv0 = ((lk)     ^ (lr & 7)) * 16;
  int chv1 = ((4 + lk) ^ (lr & 7)) * 16;
  int aof0 = 65536 + wr * 8192 + lr * 128 + chv0;
  int aof1 = 65536 + wr * 8192 + lr * 128 + chv1;
  int bof0 = wc * 4096 + lr * 128 + chv0;
  int bof1 = wc * 4096 + lr * 128 + chv1;

  f32x4 acc[8][4];
#pragma unroll
  for (int ii = 0; ii < 8; ++ii)
#pragma unroll
    for (int jj = 0; jj < 4; ++jj) acc[ii][jj] = (f32x4){0.f, 0.f, 0.f, 0.f};
  short8 af[4][2], bq0[2][2], bq1[2][2];

#define STAGE_A(p, h, kt) do { \
    size_t ko = (size_t)(kt) * 64 + (size_t)(h) * 64 * LDA; \
    gload_lds16(pA0 + ko, lds + 65536 + (p) * 32768 + (h) * 16384 + dstb); \
    gload_lds16(pA1 + ko, lds + 65536 + (p) * 32768 + (h) * 16384 + 8192 + dstb); } while (0)
#define STAGE_B(p, h, kt) do { \
    size_t ko = (size_t)(kt) * 64 + (size_t)(h) * 32 * LDB; \
    gload_lds16(pB0 + ko, lds + (p) * 32768 + (h) * 16384 + dstb); \
    gload_lds16(pB1 + ko, lds + (p) * 32768 + (h) * 16384 + 8192 + dstb); } while (0)
#define READ_A(p, mh) do { \
    _Pragma("unroll") for (int mf = 0; mf < 4; ++mf) { \
      af[mf][0] = *(const short8*)(lds + (p) * 32768 + (mh) * 16384 + mf * 2048 + aof0); \
      af[mf][1] = *(const short8*)(lds + (p) * 32768 + (mh) * 16384 + mf * 2048 + aof1); } } while (0)
#define READ_B0(p) do { \
    _Pragma("unroll") for (int nf = 0; nf < 2; ++nf) { \
      bq0[nf][0] = *(const short8*)(lds + (p) * 32768 + nf * 2048 + bof0); \
      bq0[nf][1] = *(const short8*)(lds + (p) * 32768 + nf * 2048 + bof1); } } while (0)
#define READ_B1(p) do { \
    _Pragma("unroll") for (int nf = 0; nf < 2; ++nf) { \
      bq1[nf][0] = *(const short8*)(lds + (p) * 32768 + 16384 + nf * 2048 + bof0); \
      bq1[nf][1] = *(const short8*)(lds + (p) * 32768 + 16384 + nf * 2048 + bof1); } } while (0)
#define MM16(mh, nh) do { \
    _Pragma("unroll") for (int ks = 0; ks < 2; ++ks) \
    _Pragma("unroll") for (int mf = 0; mf < 4; ++mf) \
    _Pragma("unroll") for (int nf = 0; nf < 2; ++nf) \
      acc[(mh) * 4 + mf][(nh) * 2 + nf] = __builtin_amdgcn_mfma_f32_16x16x32_bf16( \
          af[mf][ks], (nh) ? bq1[nf][ks] : bq0[nf][ks], \
          acc[(mh) * 4 + mf][(nh) * 2 + nf], 0, 0, 0); } while (0)
#define BARRIER() asm volatile("s_barrier" ::: "memory")
#define LGKM0()  do { asm volatile("s_waitcnt lgkmcnt(0)" ::: "memory"); __builtin_amdgcn_sched_barrier(0); } while (0)
#define PRIO1()  __builtin_amdgcn_s_setprio(1)
#define PRIO0()  __builtin_amdgcn_s_setprio(0)
#define BODY(t, p, S1, S2, VMN) do { \
    READ_A(p, 0); READ_B0(p); \
    if (S1) STAGE_B((p) ^ 1, 0, (t) + 1); \
    asm volatile("s_waitcnt lgkmcnt(8)" ::: "memory"); \
    BARRIER(); LGKM0(); PRIO1(); MM16(0, 0); PRIO0(); BARRIER(); \
    READ_B1(p); \
    if (S2) STAGE_A(p, 0, (t) + 2); \
    BARRIER(); LGKM0(); PRIO1(); MM16(0, 1); PRIO0(); BARRIER(); \
    READ_A(p, 1); \
    if (S2) STAGE_B(p, 1, (t) + 2); \
    BARRIER(); LGKM0(); PRIO1(); MM16(1, 1); PRIO0(); BARRIER(); \
    if (S2) STAGE_A(p, 1, (t) + 2); \
    BARRIER(); PRIO1(); MM16(1, 0); PRIO0(); \
    asm volatile("s_waitcnt vmcnt(%0)" :: "i"(VMN) : "memory"); \
    BARRIER(); } while (0)

  const int NT = Kdim >> 6;
  STAGE_A(0, 0, 0); STAGE_B(0, 0, 0); STAGE_B(0, 1, 0); STAGE_A(0, 1, 0);
  STAGE_A(1, 0, 1); STAGE_B(1, 1, 1); STAGE_A(1, 1, 1);
  asm volatile("s_waitcnt vmcnt(6)" ::: "memory");
  BARRIER();

  int t = 0;
  for (; t + 3 < NT; t += 2) {
    BODY(t, 0, 1, 1, 6);
    BODY(t + 1, 1, 1, 1, 6);
  }
  BODY(t, 0, 1, 0, 0);
  {
    READ_A(1, 0); READ_B0(1);
    BARRIER(); LGKM0(); MM16(0, 0); BARRIER();
    READ_B1(1);
    BARRIER(); LGKM0(); MM16(0, 1); BARRIER();
    READ_A(1, 1);
    BARRIER(); LGKM0(); MM16(1, 1); BARRIER();
    MM16(1, 0);
  }
#undef STAGE_A
#undef STAGE_B
#undef READ_A
#undef READ_B0
#undef READ_B1
#undef MM16
#undef BARRIER
#undef LGKM0
#undef PRIO1
#undef PRIO0
#undef BODY

  if (EPI == 4 && n0 >= 4096) {
#pragma unroll
    for (int mf = 0; mf < 8; ++mf) {
#pragma unroll
      for (int nf = 0; nf < 4; ++nf) {
        int cl = n0 + wc * 64 + nf * 16 + lr;
        int d = cl - 4096;
        int hh = d >> 7, dh = d & 127;
        int rwb = m0 + wr * 128 + mf * 16 + lk * 4;
        int bb = rwb >> 11, tt = rwb & 2047;
        float bs = bias[cl];
        short4v s;
#pragma unroll
        for (int r = 0; r < 4; ++r)
          s[r] = (short)__bfloat16_as_ushort(__float2bfloat16(acc[mf][nf][r] + bs));
        *(short4v*)(Vt + ((size_t)(bb * 16 + hh) * 128 + dh) * 2048 + tt) = s;
      }
    }
    return;
  }
#pragma unroll
  for (int mf = 0; mf < 8; ++mf) {
#pragma unroll
    for (int nf = 0; nf < 4; ++nf) {
#pragma unroll
      for (int r = 0; r < 4; ++r) {
        int rw = m0 + wr * 128 + mf * 16 + lk * 4 + r;
        int cl = n0 + wc * 64 + nf * 16 + lr;
        float v = acc[mf][nf][r];
        size_t gi = (size_t)rw * Ndim + cl;
        if (EPI == 0 || EPI == 4) {
          Cb[gi] = __float2bfloat16(v + bias[cl]);
        } else if (EPI == 1) {
          float vv = v + bias[cl];
          float u = vv * (vv * vv * 0.044715f + 1.0f) * 1.5957691216057308f; // 2*sqrt(2/pi)
          float e = __expf(u);
          float th = (e - 1.0f) / (e + 1.0f);   // tanh(u/2); R9-validated
          Cb[gi] = __float2bfloat16(0.5f * vv * (1.0f + th));
        } else {
          float add = v + (chunk == 0 ? bias[cl] : 0.0f);
          atomicAdd(&Cf[gi], add);
        }
      }
    }
  }
}

// ---------- causal flash attention + residual add ----------
// R16 defer-max + R17 deferred SUM-reduce: l kept as per-lane partial (no
// per-tile butterfly); single 4-step butterfly after the K-loop. Rare-rescale
// multiplies the per-lane partial (row-uniform alpha) -> algebra exact.
__global__ __launch_bounds__(256, 2) void k_attn(const bf16_t* __restrict__ qkv,
                                                 const bf16_t* __restrict__ vT,
                                                 const float* __restrict__ x,
                                                 float* __restrict__ out) {
  __shared__ __align__(16) bf16_t Pl[4][32][40];
  int j = blockIdx.x;
  int bh = j & 31;
  int cq = j >> 5;
  int b = bh >> 4, h = bh & 15;
  int w = threadIdx.x >> 6, lane = threadIdx.x & 63;
  int lr = lane & 15, lk = lane >> 4;
  int c = (w == 0) ? cq : (w == 1) ? (63 - cq) : (w == 2) ? (31 - cq) : (32 + cq);
  int q0 = c * 32;
  const bf16_t* qb = qkv + (size_t)(b * 2048) * 6144 + h * 128;
  const bf16_t* kb = qb + 2048;
  const bf16_t* vb = vT + (size_t)(b * 16 + h) * 128 * 2048;
  short8 qf[2][4];
#pragma unroll
  for (int qg = 0; qg < 2; ++qg)
#pragma unroll
    for (int d4 = 0; d4 < 4; ++d4)
      qf[qg][d4] = *(const short8*)(qb + (size_t)(q0 + qg * 16 + lr) * 6144 + d4 * 32 + lk * 8);
  float m[2][4], l[2][4];
#pragma unroll
  for (int qg = 0; qg < 2; ++qg)
#pragma unroll
    for (int r = 0; r < 4; ++r) { m[qg][r] = -1e30f; l[qg][r] = 0.f; }
  f32x4 o[2][8] = {};
  int nkt = c + 1;
  const float sc = 0.08838834764831845f;
  short8 kf[2][4], vf[8];
#pragma unroll
  for (int nt = 0; nt < 2; ++nt)
#pragma unroll
    for (int d4 = 0; d4 < 4; ++d4)
      kf[nt][d4] = *(const short8*)(kb + (size_t)(nt * 16 + lr) * 6144 + d4 * 32 + lk * 8);
#pragma unroll
  for (int d8 = 0; d8 < 8; ++d8)
    vf[d8] = *(const short8*)(vb + (size_t)(d8 * 16 + lr) * 2048 + lk * 8);

  for (int kt = 0; kt < nkt; ++kt) {
    int tk0 = kt * 32;
    f32x4 s[2][2] = {};
    __builtin_amdgcn_s_setprio(1);
#pragma unroll
    for (int d4 = 0; d4 < 4; ++d4)
#pragma unroll
      for (int qg = 0; qg < 2; ++qg)
#pragma unroll
        for (int nt = 0; nt < 2; ++nt)
          s[qg][nt] = __builtin_amdgcn_mfma_f32_16x16x32_bf16(qf[qg][d4], kf[nt][d4], s[qg][nt], 0, 0, 0);
    __builtin_amdgcn_s_setprio(0);
    if (kt + 1 < nkt) {
      int tn = tk0 + 32;
#pragma unroll
      for (int nt = 0; nt < 2; ++nt)
#pragma unroll
        for (int d4 = 0; d4 < 4; ++d4)
          kf[nt][d4] = *(const short8*)(kb + (size_t)(tn + nt * 16 + lr) * 6144 + d4 * 32 + lk * 8);
    }
#pragma unroll
    for (int qg = 0; qg < 2; ++qg) {
      float sv[2][4], mt[4];
#pragma unroll
      for (int r = 0; r < 4; ++r) {
        int qr = q0 + qg * 16 + lk * 4 + r;
#pragma unroll
        for (int nt = 0; nt < 2; ++nt) {
          float v = s[qg][nt][r] * sc;
          int kc = tk0 + nt * 16 + lr;
          sv[nt][r] = (kc > qr) ? -1e30f : v;
        }
        mt[r] = fmaxf(sv[0][r], sv[1][r]);
      }
      // T13 defer-max: only pay reduce + rescale when the max moved > 8.
      bool ok = true;
#pragma unroll
      for (int r = 0; r < 4; ++r) ok = ok && (mt[r] <= m[qg][r] + 8.0f);
      if (!__all(ok)) {
#pragma unroll
        for (int off = 1; off < 16; off <<= 1)
#pragma unroll
          for (int r = 0; r < 4; ++r) mt[r] = fmaxf(mt[r], __shfl_xor(mt[r], off));
        float alpha[4];
#pragma unroll
        for (int r = 0; r < 4; ++r) {
          float mn = fmaxf(m[qg][r], mt[r]);
          alpha[r] = __expf(m[qg][r] - mn);
          m[qg][r] = mn;
          l[qg][r] *= alpha[r];              // per-lane partial, row-uniform alpha
        }
#pragma unroll
        for (int d8 = 0; d8 < 8; ++d8)
#pragma unroll
          for (int r = 0; r < 4; ++r) o[qg][d8][r] *= alpha[r];
      }
      // deferred sum-reduce: accumulate per-lane partials only
#pragma unroll
      for (int r = 0; r < 4; ++r) {
        float p0 = __expf(sv[0][r] - m[qg][r]);
        float p1 = __expf(sv[1][r] - m[qg][r]);
        l[qg][r] += p0 + p1;
        Pl[w][qg * 16 + lk * 4 + r][lr]      = __float2bfloat16(p0);
        Pl[w][qg * 16 + lk * 4 + r][16 + lr] = __float2bfloat16(p1);
      }
    }
    asm volatile("s_waitcnt lgkmcnt(0)" ::: "memory");
    short8 pf[2];
#pragma unroll
    for (int qg = 0; qg < 2; ++qg)
      pf[qg] = *(const short8*)(&Pl[w][qg * 16 + lr][lk * 8]);
    __builtin_amdgcn_s_setprio(1);
#pragma unroll
    for (int d8 = 0; d8 < 8; ++d8)
#pragma unroll
      for (int qg = 0; qg < 2; ++qg)
        o[qg][d8] = __builtin_amdgcn_mfma_f32_16x16x32_bf16(pf[qg], vf[d8], o[qg][d8], 0, 0, 0);
    __builtin_amdgcn_s_setprio(0);
    if (kt + 1 < nkt) {
      int tn = tk0 + 32;
#pragma unroll
      for (int d8 = 0; d8 < 8; ++d8)
        vf[d8] = *(const short8*)(vb + (size_t)(d8 * 16 + lr) * 2048 + tn + lk * 8);
    }
  }
  // final sum butterfly (once, 4 steps over the 16-lane column group)
#pragma unroll
  for (int off = 1; off < 16; off <<= 1)
#pragma unroll
    for (int qg = 0; qg < 2; ++qg)
#pragma unroll
      for (int r = 0; r < 4; ++r) l[qg][r] += __shfl_xor(l[qg][r], off);
#pragma unroll
  for (int qg = 0; qg < 2; ++qg)
#pragma unroll
    for (int d8 = 0; d8 < 8; ++d8)
#pragma unroll
      for (int r = 0; r < 4; ++r) {
        int qr = q0 + qg * 16 + lk * 4 + r;
        int cl = h * 128 + d8 * 16 + lr;
        size_t gi = (size_t)(b * 2048 + qr) * 2048 + cl;
        out[gi] = x[gi] + o[qg][d8][r] / l[qg][r];
      }
}

extern "C" void kernel_launch(void* const* d_in, const int* in_sizes, int n_in,
                              void* d_out, int out_size, void* d_ws, size_t ws_size,
                              hipStream_t stream) {
  const float* x    = (const float*)d_in[0];
  const float* ln1s = (const float*)d_in[1];
  const float* ln1b = (const float*)d_in[2];
  const float* wqkv = (const float*)d_in[3];
  const float* bqkv = (const float*)d_in[4];
  const float* ln2s = (const float*)d_in[5];
  const float* ln2b = (const float*)d_in[6];
  const float* w1   = (const float*)d_in[7];
  const float* b1   = (const float*)d_in[8];
  const float* w2   = (const float*)d_in[9];
  const float* b2   = (const float*)d_in[10];
  float* out = (float*)d_out;
  char* ws = (char*)d_ws;

  // ws layout (bytes): r@0 16MB; qkv@16MB 48MB (V third unused); w1T@64MB 32MB;
  // w2T@96MB 32MB; h@128MB 64MB (clobbers wqkvT+vT after attention);
  // wqkvT@128MB 24MB (dead before h); vT@160MB 16MB (dead before h).
  bf16_t* r     = (bf16_t*)(ws + 0);
  bf16_t* qkv   = (bf16_t*)(ws + 16777216);
  bf16_t* w1T   = (bf16_t*)(ws + 67108864);
  bf16_t* w2T   = (bf16_t*)(ws + 100663296);
  bf16_t* h     = (bf16_t*)(ws + 134217728);
  bf16_t* wqkvT = (bf16_t*)(ws + 134217728);
  bf16_t* vT    = (bf16_t*)(ws + 167772160);

  // weight transposes (f32 [K][N] -> bf16 [N][K])
  k_transpose_cvt<<<dim3(96, 32),  256, 0, stream>>>(wqkv, wqkvT, 2048, 6144);
  k_transpose_cvt<<<dim3(128, 32), 256, 0, stream>>>(w1,   w1T,   2048, 8192);
  k_transpose_cvt<<<dim3(32, 128), 256, 0, stream>>>(w2,   w2T,   8192, 2048);
  // LN1
  k_layernorm<<<4096, 256, 0, stream>>>(x, ln1s, ln1b, r);
  // QKV (fused V-transpose): 24 n-tiles, nsub=3; 384 blocks
  k_gemm8<4><<<384, 512, 0, stream>>>(r, wqkvT, bqkv, qkv, nullptr, vT, 6144, 2048, 2048, 2048, 3);
  // attention + residual (writes every element of d_out)
  k_attn<<<512, 256, 0, stream>>>(qkv, vT, x, out);
  // LN2 on x2 = d_out
  k_layernorm<<<4096, 256, 0, stream>>>(out, ln2s, ln2b, r);
  // MLP1: 32 n-tiles, nsub=4; 512 blocks
  k_gemm8<1><<<512, 512, 0, stream>>>(r, w1T, b1, h, nullptr, nullptr, 8192, 2048, 2048, 2048, 4);
  // MLP2 split-K=2, atomicAdd epilogue: nsub=1; 256 blocks
  k_gemm8<3><<<256, 512, 0, stream>>>(h, w2T, b2, nullptr, out, nullptr, 2048, 8192, 8192, 4096, 1);
}